// Round 6
// baseline (157.060 us; speedup 1.0000x reference)
//
#include <hip/hip_runtime.h>
#include <hip/hip_cooperative_groups.h>
#include <math.h>

namespace cg = cooperative_groups;

#define NCELLS (64 * 128 * 128)        // 1,048,576
#define BLOCK 256
#define GRID 512                        // 2 blocks/CU -> co-resident with huge margin
#define NTHREADS (GRID * BLOCK)         // 131,072
#define CHUNKS_PER_THREAD 2             // 2 chunks x 4 cells = 8 cells/thread
#define NACC 6
#define WS_STRIDE 8
#define EPSV 1e-10f

__device__ __forceinline__ float sigmoidf_(float x) {
    return 1.0f / (1.0f + __expf(-x));
}
__device__ __forceinline__ float softplusf_(float x) {
    // logaddexp(0,x) = max(x,0) + log(1 + exp(-|x|))
    return fmaxf(x, 0.0f) + __logf(1.0f + __expf(-fabsf(x)));
}
__device__ __forceinline__ float iou_(float cx, float cy, float cw, float ch,
                                      float tx, float ty, float tw, float th) {
    float plx = cx - 0.5f * cw, ply = cy - 0.5f * ch;
    float prx = cx + 0.5f * cw, pry = cy + 0.5f * ch;
    float tlx = tx - 0.5f * tw, tly = ty - 0.5f * th;
    float trx = tx + 0.5f * tw, try_ = ty + 0.5f * th;
    float wx = fmaxf(fminf(prx, trx) - fmaxf(plx, tlx), 0.0f);
    float wy = fmaxf(fminf(pry, try_) - fmaxf(ply, tly), 0.0f);
    float inter = wx * wy;
    return inter / (cw * ch + tw * th - inter + EPSV);
}

__global__ __launch_bounds__(BLOCK) void yolo_coop_kernel(
        const float4* __restrict__ in4,
        const float4* __restrict__ tg4,
        float* __restrict__ ws,
        float* __restrict__ out) {
    const int t = threadIdx.x;
    const int tid = blockIdx.x * BLOCK + t;

    float m_cnt = 0.0f, s_noobj = 0.0f, s_nresp = 0.0f;
    float s_xy = 0.0f, s_wh = 0.0f, s_obj = 0.0f;

    // 2 chunks of 4 cells, chunks interleaved across all threads so each
    // pass is wave-dense (64 lanes x 160B contiguous input / 80B target).
    // unroll 1: halves VGPR pressure vs hoisting all 30 loads (round-4 lesson:
    // protect the register budget).
    #pragma unroll 1
    for (int h = 0; h < CHUNKS_PER_THREAD; ++h) {
        const int ch = h * NTHREADS + tid;     // chunk of 4 cells
        float r[40], tg[20];
        const float4* __restrict__ ip = in4 + (size_t)ch * 10;
        #pragma unroll
        for (int i = 0; i < 10; ++i) {
            float4 v = ip[i];
            r[4*i] = v.x; r[4*i+1] = v.y; r[4*i+2] = v.z; r[4*i+3] = v.w;
        }
        const float4* __restrict__ tp = tg4 + (size_t)ch * 5;
        #pragma unroll
        for (int i = 0; i < 5; ++i) {
            float4 v = tp[i];
            tg[4*i] = v.x; tg[4*i+1] = v.y; tg[4*i+2] = v.z; tg[4*i+3] = v.w;
        }

        #pragma unroll
        for (int j = 0; j < 4; ++j) {
            const float* f = r + j * 10;   // [logit0, x0,y0,w0,h0, logit1, x1,y1,w1,h1]
            const float* tt = tg + j * 5;  // [conf, tx,ty,tw,th]

            float logit0 = f[0], logit1 = f[5];
            float bce0_0 = softplusf_(logit0);
            float bce0_1 = softplusf_(logit1);

            float tx = tt[1], ty = tt[2], tw = tt[3], th = tt[4];
            bool obj = (tt[0] > 0.0f);

            if (!obj) {
                s_noobj += bce0_0 + bce0_1;
            } else {
                m_cnt += 1.0f;
                float cx0 = sigmoidf_(f[1]), cy0 = sigmoidf_(f[2]);
                float cw0 = sigmoidf_(f[3]), ch0 = sigmoidf_(f[4]);
                float cx1 = sigmoidf_(f[6]), cy1 = sigmoidf_(f[7]);
                float cw1 = sigmoidf_(f[8]), ch1 = sigmoidf_(f[9]);

                float iou0 = iou_(cx0, cy0, cw0, ch0, tx, ty, tw, th);
                float iou1 = iou_(cx1, cy1, cw1, ch1, tx, ty, tw, th);
                bool r1 = (iou1 > iou0);   // argmax first-index tie-break

                float rcx = r1 ? cx1 : cx0, rcy = r1 ? cy1 : cy0;
                float rcw = r1 ? cw1 : cw0, rch = r1 ? ch1 : ch0;
                float dx = rcx - tx, dy = rcy - ty;
                float dw = rcw - tw, dh = rch - th;
                s_xy += dx * dx + dy * dy;
                s_wh += dw * dw + dh * dh;
                s_obj += r1 ? (bce0_1 - logit1) : (bce0_0 - logit0);
                s_nresp += r1 ? bce0_0 : bce0_1;
            }
        }
    }

    // one butterfly reduce per block
    float vals[NACC] = {m_cnt, s_noobj, s_nresp, s_xy, s_wh, s_obj};
    #pragma unroll
    for (int i = 0; i < NACC; ++i) {
        float v = vals[i];
        #pragma unroll
        for (int off = 32; off > 0; off >>= 1) v += __shfl_down(v, off, 64);
        vals[i] = v;
    }

    __shared__ float sm[4][NACC];
    int wave = t >> 6, lane = t & 63;
    if (lane == 0) {
        #pragma unroll
        for (int i = 0; i < NACC; ++i) sm[wave][i] = vals[i];
    }
    __syncthreads();

    if (t < NACC) {
        ws[(size_t)blockIdx.x * WS_STRIDE + t] = sm[0][t] + sm[1][t] + sm[2][t] + sm[3][t];
    }

    cg::this_grid().sync();

    // block 0 reduces the 512 x 6 table and writes outputs
    if (blockIdx.x == 0) {
        float acc[NACC] = {0, 0, 0, 0, 0, 0};
        for (int b = t; b < GRID; b += BLOCK) {
            #pragma unroll
            for (int i = 0; i < NACC; ++i) acc[i] += ws[(size_t)b * WS_STRIDE + i];
        }
        #pragma unroll
        for (int i = 0; i < NACC; ++i) {
            float v = acc[i];
            #pragma unroll
            for (int off = 32; off > 0; off >>= 1) v += __shfl_down(v, off, 64);
            acc[i] = v;
        }
        __shared__ float sm2[4][NACC];
        if (lane == 0) {
            #pragma unroll
            for (int i = 0; i < NACC; ++i) sm2[wave][i] = acc[i];
        }
        __syncthreads();
        if (t == 0) {
            float tot[NACC];
            #pragma unroll
            for (int i = 0; i < NACC; ++i)
                tot[i] = sm2[0][i] + sm2[1][i] + sm2[2][i] + sm2[3][i];
            float m = tot[0];
            float n_noobj = (float)NCELLS - m;
            float loss_noobj = tot[1] / (n_noobj * 2.0f) + tot[2] / m;  // B=2 -> (B-1)=1
            float loss_xy = tot[3] / (m * 2.0f);
            float loss_wh = tot[4] / (m * 2.0f);
            float loss_obj = tot[5] / m;
            out[0] = loss_noobj + loss_xy + loss_wh + loss_obj;
            out[1] = loss_noobj;
            out[2] = loss_xy;
            out[3] = loss_wh;
            out[4] = loss_obj;
        }
    }
}

extern "C" void kernel_launch(void* const* d_in, const int* in_sizes, int n_in,
                              void* d_out, int out_size, void* d_ws, size_t ws_size,
                              hipStream_t stream) {
    const float4* in4 = (const float4*)d_in[0];
    const float4* tg4 = (const float4*)d_in[1];
    float* out = (float*)d_out;
    float* ws = (float*)d_ws;

    void* args[] = {(void*)&in4, (void*)&tg4, (void*)&ws, (void*)&out};
    hipLaunchCooperativeKernel((const void*)yolo_coop_kernel,
                               dim3(GRID), dim3(BLOCK), args, 0, stream);
}

// Round 8
// 98.508 us; speedup vs baseline: 1.5944x; 1.5944x over previous
//
#include <hip/hip_runtime.h>
#include <math.h>

#define NCELLS (64 * 128 * 128)        // 1,048,576
#define BLOCK 256
#define GRID 2048                       // 8 blocks/CU co-resident
#define CPT 2                           // contiguous cells per thread
#define NACC 6
#define NSLOT 64
#define SLOT_STRIDE 16                  // 64 B per slot -> one cache line each
#define EPSV 1e-10f

// ws layout: 64 slots x 16 floats (4 KB, zeroed by memset node each launch).
// slot[s][0..5] = {m, s_noobj, s_nresp, s_xy, s_wh, s_obj} partial sums.
// Block b accumulates into slot b&63 -> ~32 blocks/line, negligible contention.

__device__ __forceinline__ float sigmoidf_(float x) {
    return 1.0f / (1.0f + __expf(-x));
}
__device__ __forceinline__ float softplusf_(float x) {
    // logaddexp(0,x) = max(x,0) + log(1 + exp(-|x|))
    return fmaxf(x, 0.0f) + __logf(1.0f + __expf(-fabsf(x)));
}
__device__ __forceinline__ float iou_(float cx, float cy, float cw, float ch,
                                      float tx, float ty, float tw, float th) {
    float plx = cx - 0.5f * cw, ply = cy - 0.5f * ch;
    float prx = cx + 0.5f * cw, pry = cy + 0.5f * ch;
    float tlx = tx - 0.5f * tw, tly = ty - 0.5f * th;
    float trx = tx + 0.5f * tw, try_ = ty + 0.5f * th;
    float wx = fmaxf(fminf(prx, trx) - fmaxf(plx, tlx), 0.0f);
    float wy = fmaxf(fminf(pry, try_) - fmaxf(ply, tly), 0.0f);
    float inter = wx * wy;
    return inter / (cw * ch + tw * th - inter + EPSV);
}

__global__ __launch_bounds__(BLOCK) void yolo_main_kernel(
        const float4* __restrict__ in4,
        const float2* __restrict__ tg2,
        float* __restrict__ ws) {
    const int t = threadIdx.x;
    const int tid = blockIdx.x * BLOCK + t;

    // 2 contiguous cells/thread: input = 5 float4 (80 B, 16B-aligned),
    // target = 5 float2 (40 B, 8B-aligned). 10 loads in flight per thread.
    float r[20], tg[10];
    const float4* __restrict__ ip = in4 + (size_t)tid * 5;
    #pragma unroll
    for (int i = 0; i < 5; ++i) {
        float4 v = ip[i];
        r[4*i] = v.x; r[4*i+1] = v.y; r[4*i+2] = v.z; r[4*i+3] = v.w;
    }
    const float2* __restrict__ tp = tg2 + (size_t)tid * 5;
    #pragma unroll
    for (int i = 0; i < 5; ++i) {
        float2 v = tp[i];
        tg[2*i] = v.x; tg[2*i+1] = v.y;
    }

    float m_cnt = 0.0f, s_noobj = 0.0f, s_nresp = 0.0f;
    float s_xy = 0.0f, s_wh = 0.0f, s_obj = 0.0f;

    #pragma unroll
    for (int j = 0; j < CPT; ++j) {
        const float* f = r + j * 10;   // [logit0, x0,y0,w0,h0, logit1, x1,y1,w1,h1]
        const float* tt = tg + j * 5;  // [conf, tx,ty,tw,th]

        float logit0 = f[0], logit1 = f[5];
        float bce0_0 = softplusf_(logit0);
        float bce0_1 = softplusf_(logit1);

        float tx = tt[1], ty = tt[2], tw = tt[3], th = tt[4];
        bool obj = (tt[0] > 0.0f);

        if (!obj) {
            s_noobj += bce0_0 + bce0_1;
        } else {
            m_cnt += 1.0f;
            float cx0 = sigmoidf_(f[1]), cy0 = sigmoidf_(f[2]);
            float cw0 = sigmoidf_(f[3]), ch0 = sigmoidf_(f[4]);
            float cx1 = sigmoidf_(f[6]), cy1 = sigmoidf_(f[7]);
            float cw1 = sigmoidf_(f[8]), ch1 = sigmoidf_(f[9]);

            float iou0 = iou_(cx0, cy0, cw0, ch0, tx, ty, tw, th);
            float iou1 = iou_(cx1, cy1, cw1, ch1, tx, ty, tw, th);
            bool r1 = (iou1 > iou0);   // argmax first-index tie-break

            float rcx = r1 ? cx1 : cx0, rcy = r1 ? cy1 : cy0;
            float rcw = r1 ? cw1 : cw0, rch = r1 ? ch1 : ch0;
            float dx = rcx - tx, dy = rcy - ty;
            float dw = rcw - tw, dh = rch - th;
            s_xy += dx * dx + dy * dy;
            s_wh += dw * dw + dh * dh;
            s_obj += r1 ? (bce0_1 - logit1) : (bce0_0 - logit0);
            s_nresp += r1 ? bce0_0 : bce0_1;
        }
    }

    // 64-lane butterfly reduce, then cross-wave via LDS
    float vals[NACC] = {m_cnt, s_noobj, s_nresp, s_xy, s_wh, s_obj};
    #pragma unroll
    for (int i = 0; i < NACC; ++i) {
        float v = vals[i];
        #pragma unroll
        for (int off = 32; off > 0; off >>= 1) v += __shfl_down(v, off, 64);
        vals[i] = v;
    }

    __shared__ float sm[4][NACC];
    int wave = t >> 6, lane = t & 63;
    if (lane == 0) {
        #pragma unroll
        for (int i = 0; i < NACC; ++i) sm[wave][i] = vals[i];
    }
    __syncthreads();

    // striped accumulator slots: ~32 blocks per line, 6 atomics each
    if (t < NACC) {
        float s = sm[0][t] + sm[1][t] + sm[2][t] + sm[3][t];
        atomicAdd(&ws[(size_t)(blockIdx.x & (NSLOT - 1)) * SLOT_STRIDE + t], s);
    }
}

__global__ __launch_bounds__(64) void yolo_finalize_kernel(
        const float* __restrict__ ws, float* __restrict__ out) {
    const int l = threadIdx.x;           // one wave; lane l owns slot l
    float v[NACC];
    #pragma unroll
    for (int i = 0; i < NACC; ++i) v[i] = ws[(size_t)l * SLOT_STRIDE + i];
    #pragma unroll
    for (int i = 0; i < NACC; ++i) {
        #pragma unroll
        for (int off = 32; off > 0; off >>= 1) v[i] += __shfl_down(v[i], off, 64);
    }
    if (l == 0) {
        float m = v[0];
        float n_noobj = (float)NCELLS - m;
        float loss_noobj = v[1] / (n_noobj * 2.0f) + v[2] / m;  // B=2 -> (B-1)=1
        float loss_xy = v[3] / (m * 2.0f);
        float loss_wh = v[4] / (m * 2.0f);
        float loss_obj = v[5] / m;
        out[0] = loss_noobj + loss_xy + loss_wh + loss_obj;
        out[1] = loss_noobj;
        out[2] = loss_xy;
        out[3] = loss_wh;
        out[4] = loss_obj;
    }
}

extern "C" void kernel_launch(void* const* d_in, const int* in_sizes, int n_in,
                              void* d_out, int out_size, void* d_ws, size_t ws_size,
                              hipStream_t stream) {
    const float4* in4 = (const float4*)d_in[0];
    const float2* tg2 = (const float2*)d_in[1];
    float* out = (float*)d_out;
    float* ws = (float*)d_ws;

    hipMemsetAsync(ws, 0, NSLOT * SLOT_STRIDE * sizeof(float), stream);  // 4 KB
    hipLaunchKernelGGL(yolo_main_kernel, dim3(GRID), dim3(BLOCK), 0, stream,
                       in4, tg2, ws);
    hipLaunchKernelGGL(yolo_finalize_kernel, dim3(1), dim3(64), 0, stream, ws, out);
}